// Round 3
// baseline (662.348 us; speedup 1.0000x reference)
//
#include <hip/hip_runtime.h>

// Message passing, gather formulation with packed CSR entries.
// For edge e=(s,d): out[d] += r[s]*ev ; out[s] += r[d]*ev.
// Entry k in [0, 2E): edge = k>>1, j = k&1.
//   center = a[2*edge + (j^1)]   (row of out that accumulates)
//   other  = a[2*edge + j]       (row of r that is gathered)
// CSR build in d_ws: degree histogram -> scan -> fill packed int2{edge,other}
// sorted by center. Gather: one wave per node, unroll x4, register acc,
// single coalesced float2 store per lane. No atomics on out, no out memset.

#define D_FEAT 128
#define SCAN_THREADS 1024

__global__ void hist_kernel(const int* __restrict__ a, int* __restrict__ deg,
                            int n_elems) {
    int i = blockIdx.x * blockDim.x + threadIdx.x;
    if (i < n_elems) atomicAdd(&deg[a[i]], 1);
}

// Single-block exclusive scan over n_nodes counters.
__global__ void scan_kernel(int* __restrict__ deg, int* __restrict__ offs,
                            int n_nodes) {
    __shared__ int lds[SCAN_THREADS];
    int t = threadIdx.x;
    int chunk = (n_nodes + SCAN_THREADS - 1) / SCAN_THREADS;
    int base = t * chunk;
    int endi = min(base + chunk, n_nodes);
    int s = 0;
    for (int i = base; i < endi; ++i) s += deg[i];
    lds[t] = s;
    __syncthreads();
    for (int off = 1; off < SCAN_THREADS; off <<= 1) {
        int v = (t >= off) ? lds[t - off] : 0;
        __syncthreads();
        lds[t] += v;
        __syncthreads();
    }
    int excl = (t == 0) ? 0 : lds[t - 1];
    int total = lds[SCAN_THREADS - 1];
    int p = excl;
    for (int i = base; i < endi; ++i) {
        int v = deg[i];
        offs[i] = p;
        deg[i] = p;   // cursor start for fill phase
        p += v;
    }
    if (t == 0) offs[n_nodes] = total;
}

__global__ void fill_kernel(const int* __restrict__ a, int* __restrict__ cursor,
                            int2* __restrict__ pl, int n_entries) {
    int k = blockIdx.x * blockDim.x + threadIdx.x;
    if (k >= n_entries) return;
    int edge = k >> 1, j = k & 1;
    int other  = a[2 * edge + j];
    int center = a[2 * edge + (j ^ 1)];
    int pos = atomicAdd(&cursor[center], 1);
    pl[pos] = make_int2(edge, other);
}

__global__ __launch_bounds__(256) void gather_kernel(
    const float* __restrict__ r, const float* __restrict__ e,
    const int* __restrict__ offs, const int2* __restrict__ pl,
    float* __restrict__ out, int n_nodes) {
    int n = blockIdx.x * 4 + (threadIdx.x >> 6);
    if (n >= n_nodes) return;
    int lane = threadIdx.x & 63;      // covers feats 2*lane, 2*lane+1
    int start = offs[n];
    int end = offs[n + 1];
    float accx = 0.f, accy = 0.f;
    int i = start;
    for (; i + 4 <= end; i += 4) {
        int2 p0 = pl[i];
        int2 p1 = pl[i + 1];
        int2 p2 = pl[i + 2];
        int2 p3 = pl[i + 3];
        const float2* e0 = (const float2*)(e + (size_t)p0.x * D_FEAT) + lane;
        const float2* r0 = (const float2*)(r + (size_t)p0.y * D_FEAT) + lane;
        const float2* e1 = (const float2*)(e + (size_t)p1.x * D_FEAT) + lane;
        const float2* r1 = (const float2*)(r + (size_t)p1.y * D_FEAT) + lane;
        const float2* e2 = (const float2*)(e + (size_t)p2.x * D_FEAT) + lane;
        const float2* r2 = (const float2*)(r + (size_t)p2.y * D_FEAT) + lane;
        const float2* e3 = (const float2*)(e + (size_t)p3.x * D_FEAT) + lane;
        const float2* r3 = (const float2*)(r + (size_t)p3.y * D_FEAT) + lane;
        float2 ev0 = *e0, rv0 = *r0;
        float2 ev1 = *e1, rv1 = *r1;
        float2 ev2 = *e2, rv2 = *r2;
        float2 ev3 = *e3, rv3 = *r3;
        accx += ev0.x * rv0.x; accy += ev0.y * rv0.y;
        accx += ev1.x * rv1.x; accy += ev1.y * rv1.y;
        accx += ev2.x * rv2.x; accy += ev2.y * rv2.y;
        accx += ev3.x * rv3.x; accy += ev3.y * rv3.y;
    }
    for (; i < end; ++i) {
        int2 p0 = pl[i];
        float2 ev0 = *((const float2*)(e + (size_t)p0.x * D_FEAT) + lane);
        float2 rv0 = *((const float2*)(r + (size_t)p0.y * D_FEAT) + lane);
        accx += ev0.x * rv0.x;
        accy += ev0.y * rv0.y;
    }
    float2 res;
    res.x = accx;
    res.y = accy;
    *((float2*)(out + (size_t)n * D_FEAT) + lane) = res;
}

// ---- fallback (round-1 atomic scatter) if ws too small ----
__global__ void mp_scatter_kernel(const float* __restrict__ r,
                                  const float* __restrict__ e,
                                  const int* __restrict__ a,
                                  float* __restrict__ out,
                                  int n_edges) {
    long long gid = (long long)blockIdx.x * blockDim.x + threadIdx.x;
    int edge = (int)(gid >> 7);
    int feat = (int)(gid & 127);
    if (edge >= n_edges) return;
    int s = a[2 * edge];
    int d = a[2 * edge + 1];
    float ev = e[(long long)edge * D_FEAT + feat];
    float rs = r[(long long)s * D_FEAT + feat];
    float rd = r[(long long)d * D_FEAT + feat];
    atomicAdd(&out[(long long)d * D_FEAT + feat], rs * ev);
    atomicAdd(&out[(long long)s * D_FEAT + feat], rd * ev);
}

extern "C" void kernel_launch(void* const* d_in, const int* in_sizes, int n_in,
                              void* d_out, int out_size, void* d_ws, size_t ws_size,
                              hipStream_t stream) {
    const float* r = (const float*)d_in[0];
    const float* e = (const float*)d_in[1];
    const int*   a = (const int*)d_in[2];
    float* out = (float*)d_out;

    int n_nodes   = in_sizes[0] / D_FEAT;
    int n_edges   = in_sizes[1] / D_FEAT;
    int n_entries = 2 * n_edges;

    // ws layout: deg[N] | offs[N+1] | pad to 8B | pl[2E] (int2)
    size_t ints_head = (size_t)n_nodes + (size_t)(n_nodes + 1);
    ints_head = (ints_head + 1) & ~(size_t)1;   // 8B-align pl
    size_t need = ints_head * sizeof(int) + (size_t)n_entries * sizeof(int2);
    if (ws_size < need) {
        hipMemsetAsync(d_out, 0, (size_t)out_size * sizeof(float), stream);
        long long total = (long long)n_edges * D_FEAT;
        int block = 256;
        long long grid = (total + block - 1) / block;
        mp_scatter_kernel<<<(int)grid, block, 0, stream>>>(r, e, a, out, n_edges);
        return;
    }

    int*  deg  = (int*)d_ws;                 // N
    int*  offs = deg + n_nodes;              // N+1
    int2* pl   = (int2*)((int*)d_ws + ints_head);  // 2E packed entries

    hipMemsetAsync(deg, 0, (size_t)n_nodes * sizeof(int), stream);

    int block = 256;
    int grid_e = (n_entries + block - 1) / block;
    hist_kernel<<<grid_e, block, 0, stream>>>(a, deg, n_entries);
    scan_kernel<<<1, SCAN_THREADS, 0, stream>>>(deg, offs, n_nodes);
    fill_kernel<<<grid_e, block, 0, stream>>>(a, deg, pl, n_entries);
    int grid_g = (n_nodes + 3) / 4;
    gather_kernel<<<grid_g, 256, 0, stream>>>(r, e, offs, pl, out, n_nodes);
}

// Round 4
// 621.509 us; speedup vs baseline: 1.0657x; 1.0657x over previous
//
#include <hip/hip_runtime.h>

// Message passing, gather formulation, bf16-compressed edge features.
// For edge (s,d): out[d] += r[s]*e_k ; out[s] += r[d]*e_k.
// Pipeline (main path, ws >= ~137 MB):
//   memset(deg) -> prep (stream e -> bf16 in ws, fused degree histogram)
//   -> scan (coalesced single-block) -> fill (packed int2{edge,other} CSR)
//   -> gather16 (one wave per node, 256B bf16 e-rows, fp32 r, register acc).
// Rationale: random-granule HBM line rate measured ~45 G lines/s (r2 vs r3
// invariant); bf16 e halves the random lines AND fits LLC (128 MB) so the
// second read of each edge row hits Infinity Cache.

#define D_FEAT 128

// ---------- bf16 pack/unpack (RNE, finite inputs) ----------
__device__ inline unsigned bf16pack2(float a, float b) {
    unsigned ua = __float_as_uint(a), ub = __float_as_uint(b);
    ua += 0x7fffu + ((ua >> 16) & 1u);
    ub += 0x7fffu + ((ub >> 16) & 1u);
    return ((ua >> 16) & 0xffffu) | (ub & 0xffff0000u);
}

// ---------- main-path kernels ----------
__global__ void prep_kernel(const float* __restrict__ e,
                            const int* __restrict__ a,
                            uint2* __restrict__ e16,      // 64M bf16 as uint2/4
                            int* __restrict__ deg,
                            int n_e4, int n_entries) {
    int gid = blockIdx.x * blockDim.x + threadIdx.x;
    if (gid < n_entries) atomicAdd(&deg[a[gid]], 1);
    if (gid >= n_e4) return;
    const float4 v = ((const float4*)e)[gid];
    uint2 p;
    p.x = bf16pack2(v.x, v.y);
    p.y = bf16pack2(v.z, v.w);
    e16[gid] = p;
}

// Coalesced tiled single-block exclusive scan (1024 threads).
__global__ void scan_kernel(int* __restrict__ deg, int* __restrict__ offs,
                            int n_nodes) {
    __shared__ int wsum[16];
    __shared__ int carry_s;
    int t = threadIdx.x;
    int lane = t & 63, w = t >> 6;
    if (t == 0) carry_s = 0;
    __syncthreads();
    for (int base = 0; base < n_nodes; base += 1024) {
        int i = base + t;
        int v = (i < n_nodes) ? deg[i] : 0;
        int x = v;
        #pragma unroll
        for (int off = 1; off < 64; off <<= 1) {
            int y = __shfl_up(x, off, 64);
            if (lane >= off) x += y;
        }
        if (lane == 63) wsum[w] = x;
        __syncthreads();
        if (w == 0 && lane < 16) {
            int s = wsum[lane];
            #pragma unroll
            for (int off = 1; off < 16; off <<= 1) {
                int y = __shfl_up(s, off, 64);
                if (lane >= off) s += y;
            }
            wsum[lane] = s;
        }
        __syncthreads();
        int wbase = (w == 0) ? 0 : wsum[w - 1];
        int incl = x + wbase + carry_s;
        if (i < n_nodes) {
            int excl = incl - v;
            offs[i] = excl;
            deg[i] = excl;   // cursor for fill phase
        }
        __syncthreads();
        if (t == 1023) carry_s = incl;
        __syncthreads();
    }
    if (t == 0) offs[n_nodes] = carry_s;
}

__global__ void fill_kernel(const int* __restrict__ a, int* __restrict__ cursor,
                            int2* __restrict__ pl, int n_entries) {
    int k = blockIdx.x * blockDim.x + threadIdx.x;
    if (k >= n_entries) return;
    int edge = k >> 1, j = k & 1;
    int other  = a[2 * edge + j];
    int center = a[2 * edge + (j ^ 1)];
    int pos = atomicAdd(&cursor[center], 1);
    pl[pos] = make_int2(edge, other);
}

__global__ __launch_bounds__(256) void gather16_kernel(
    const float* __restrict__ r, const unsigned* __restrict__ e16,
    const int* __restrict__ offs, const int2* __restrict__ pl,
    float* __restrict__ out, int n_nodes) {
    int n = blockIdx.x * 4 + (threadIdx.x >> 6);
    if (n >= n_nodes) return;
    int lane = threadIdx.x & 63;      // feats 2*lane, 2*lane+1
    int start = offs[n];
    int end = offs[n + 1];
    float accx = 0.f, accy = 0.f;
    int i = start;
    for (; i + 4 <= end; i += 4) {
        int2 p0 = pl[i];
        int2 p1 = pl[i + 1];
        int2 p2 = pl[i + 2];
        int2 p3 = pl[i + 3];
        unsigned w0 = e16[(size_t)p0.x * 64 + lane];
        float2  rv0 = *((const float2*)(r + (size_t)p0.y * D_FEAT) + lane);
        unsigned w1 = e16[(size_t)p1.x * 64 + lane];
        float2  rv1 = *((const float2*)(r + (size_t)p1.y * D_FEAT) + lane);
        unsigned w2 = e16[(size_t)p2.x * 64 + lane];
        float2  rv2 = *((const float2*)(r + (size_t)p2.y * D_FEAT) + lane);
        unsigned w3 = e16[(size_t)p3.x * 64 + lane];
        float2  rv3 = *((const float2*)(r + (size_t)p3.y * D_FEAT) + lane);
        accx += __uint_as_float(w0 << 16) * rv0.x;
        accy += __uint_as_float(w0 & 0xffff0000u) * rv0.y;
        accx += __uint_as_float(w1 << 16) * rv1.x;
        accy += __uint_as_float(w1 & 0xffff0000u) * rv1.y;
        accx += __uint_as_float(w2 << 16) * rv2.x;
        accy += __uint_as_float(w2 & 0xffff0000u) * rv2.y;
        accx += __uint_as_float(w3 << 16) * rv3.x;
        accy += __uint_as_float(w3 & 0xffff0000u) * rv3.y;
    }
    for (; i < end; ++i) {
        int2 p0 = pl[i];
        unsigned w0 = e16[(size_t)p0.x * 64 + lane];
        float2  rv0 = *((const float2*)(r + (size_t)p0.y * D_FEAT) + lane);
        accx += __uint_as_float(w0 << 16) * rv0.x;
        accy += __uint_as_float(w0 & 0xffff0000u) * rv0.y;
    }
    float2 res;
    res.x = accx;
    res.y = accy;
    *((float2*)(out + (size_t)n * D_FEAT) + lane) = res;
}

// ---------- fallback 1: fp32 gather (round-3 path) ----------
__global__ void hist_kernel(const int* __restrict__ a, int* __restrict__ deg,
                            int n_elems) {
    int i = blockIdx.x * blockDim.x + threadIdx.x;
    if (i < n_elems) atomicAdd(&deg[a[i]], 1);
}

__global__ __launch_bounds__(256) void gather_f32_kernel(
    const float* __restrict__ r, const float* __restrict__ e,
    const int* __restrict__ offs, const int2* __restrict__ pl,
    float* __restrict__ out, int n_nodes) {
    int n = blockIdx.x * 4 + (threadIdx.x >> 6);
    if (n >= n_nodes) return;
    int lane = threadIdx.x & 63;
    int start = offs[n];
    int end = offs[n + 1];
    float accx = 0.f, accy = 0.f;
    int i = start;
    for (; i + 4 <= end; i += 4) {
        int2 p0 = pl[i];
        int2 p1 = pl[i + 1];
        int2 p2 = pl[i + 2];
        int2 p3 = pl[i + 3];
        float2 ev0 = *((const float2*)(e + (size_t)p0.x * D_FEAT) + lane);
        float2 rv0 = *((const float2*)(r + (size_t)p0.y * D_FEAT) + lane);
        float2 ev1 = *((const float2*)(e + (size_t)p1.x * D_FEAT) + lane);
        float2 rv1 = *((const float2*)(r + (size_t)p1.y * D_FEAT) + lane);
        float2 ev2 = *((const float2*)(e + (size_t)p2.x * D_FEAT) + lane);
        float2 rv2 = *((const float2*)(r + (size_t)p2.y * D_FEAT) + lane);
        float2 ev3 = *((const float2*)(e + (size_t)p3.x * D_FEAT) + lane);
        float2 rv3 = *((const float2*)(r + (size_t)p3.y * D_FEAT) + lane);
        accx += ev0.x * rv0.x; accy += ev0.y * rv0.y;
        accx += ev1.x * rv1.x; accy += ev1.y * rv1.y;
        accx += ev2.x * rv2.x; accy += ev2.y * rv2.y;
        accx += ev3.x * rv3.x; accy += ev3.y * rv3.y;
    }
    for (; i < end; ++i) {
        int2 p0 = pl[i];
        float2 ev0 = *((const float2*)(e + (size_t)p0.x * D_FEAT) + lane);
        float2 rv0 = *((const float2*)(r + (size_t)p0.y * D_FEAT) + lane);
        accx += ev0.x * rv0.x;
        accy += ev0.y * rv0.y;
    }
    float2 res;
    res.x = accx;
    res.y = accy;
    *((float2*)(out + (size_t)n * D_FEAT) + lane) = res;
}

// ---------- fallback 2: atomic scatter (round-1 path) ----------
__global__ void mp_scatter_kernel(const float* __restrict__ r,
                                  const float* __restrict__ e,
                                  const int* __restrict__ a,
                                  float* __restrict__ out,
                                  int n_edges) {
    long long gid = (long long)blockIdx.x * blockDim.x + threadIdx.x;
    int edge = (int)(gid >> 7);
    int feat = (int)(gid & 127);
    if (edge >= n_edges) return;
    int s = a[2 * edge];
    int d = a[2 * edge + 1];
    float ev = e[(long long)edge * D_FEAT + feat];
    float rs = r[(long long)s * D_FEAT + feat];
    float rd = r[(long long)d * D_FEAT + feat];
    atomicAdd(&out[(long long)d * D_FEAT + feat], rs * ev);
    atomicAdd(&out[(long long)s * D_FEAT + feat], rd * ev);
}

extern "C" void kernel_launch(void* const* d_in, const int* in_sizes, int n_in,
                              void* d_out, int out_size, void* d_ws, size_t ws_size,
                              hipStream_t stream) {
    const float* r = (const float*)d_in[0];
    const float* e = (const float*)d_in[1];
    const int*   a = (const int*)d_in[2];
    float* out = (float*)d_out;

    int n_nodes   = in_sizes[0] / D_FEAT;
    int n_edges   = in_sizes[1] / D_FEAT;
    int n_entries = 2 * n_edges;
    int n_efloats = in_sizes[1];
    int n_e4      = n_efloats / 4;      // float4 groups == uint2 groups of e16

    int block = 256;
    int grid_e = (n_entries + block - 1) / block;

    // ---- main path: e16[n_e4 uint2] | deg[N] | offs[N+1] | pad | pl[2E int2]
    {
        size_t ints_head = (size_t)n_nodes + (size_t)(n_nodes + 1);
        ints_head = (ints_head + 1) & ~(size_t)1;
        size_t need = (size_t)n_e4 * sizeof(uint2)
                    + ints_head * sizeof(int)
                    + (size_t)n_entries * sizeof(int2);
        if (ws_size >= need) {
            uint2* e16  = (uint2*)d_ws;
            int*   deg  = (int*)(e16 + n_e4);
            int*   offs = deg + n_nodes;
            int2*  pl   = (int2*)((int*)(e16 + n_e4) + ints_head);

            hipMemsetAsync(deg, 0, (size_t)n_nodes * sizeof(int), stream);
            int grid_p = (n_e4 + block - 1) / block;
            prep_kernel<<<grid_p, block, 0, stream>>>(e, a, e16, deg,
                                                      n_e4, n_entries);
            scan_kernel<<<1, 1024, 0, stream>>>(deg, offs, n_nodes);
            fill_kernel<<<grid_e, block, 0, stream>>>(a, deg, pl, n_entries);
            int grid_g = (n_nodes + 3) / 4;
            gather16_kernel<<<grid_g, 256, 0, stream>>>(
                r, (const unsigned*)e16, offs, pl, out, n_nodes);
            return;
        }
    }

    // ---- fallback 1: fp32 gather (round-3 path)
    {
        size_t ints_head = (size_t)n_nodes + (size_t)(n_nodes + 1);
        ints_head = (ints_head + 1) & ~(size_t)1;
        size_t need = ints_head * sizeof(int) + (size_t)n_entries * sizeof(int2);
        if (ws_size >= need) {
            int*  deg  = (int*)d_ws;
            int*  offs = deg + n_nodes;
            int2* pl   = (int2*)((int*)d_ws + ints_head);

            hipMemsetAsync(deg, 0, (size_t)n_nodes * sizeof(int), stream);
            hist_kernel<<<grid_e, block, 0, stream>>>(a, deg, n_entries);
            scan_kernel<<<1, 1024, 0, stream>>>(deg, offs, n_nodes);
            fill_kernel<<<grid_e, block, 0, stream>>>(a, deg, pl, n_entries);
            int grid_g = (n_nodes + 3) / 4;
            gather_f32_kernel<<<grid_g, 256, 0, stream>>>(r, e, offs, pl, out,
                                                          n_nodes);
            return;
        }
    }

    // ---- fallback 2: atomic scatter
    hipMemsetAsync(d_out, 0, (size_t)out_size * sizeof(float), stream);
    long long total = (long long)n_edges * D_FEAT;
    long long grid = (total + block - 1) / block;
    mp_scatter_kernel<<<(int)grid, block, 0, stream>>>(r, e, a, out, n_edges);
}

// Round 5
// 556.238 us; speedup vs baseline: 1.1908x; 1.1173x over previous
//
#include <hip/hip_runtime.h>

// Message passing, gather formulation, bf16-compressed e AND r.
// For edge (s,d): out[d] += r[s]*e_k ; out[s] += r[d]*e_k.
// Pipeline: prep (stream e,r -> bf16 in ws, fused degree histogram)
//   -> 3-kernel multi-block scan -> fill (packed int2{edge,other} CSR)
//   -> gather (one wave per node; 256B bf16 rows: 1 uint/lane; fp32 acc).
// r16 (12.8 MB) fits in aggregate L2 -> the 1M random r reads become cache
// hits; e16 (128 MB) < 256 MB LLC -> second touch of each edge row hits LLC.

#define D_FEAT 128
#define SCAN_TILE 1024

// ---------- bf16 pack (RNE, finite inputs) ----------
__device__ inline unsigned bf16pack2(float a, float b) {
    unsigned ua = __float_as_uint(a), ub = __float_as_uint(b);
    ua += 0x7fffu + ((ua >> 16) & 1u);
    ub += 0x7fffu + ((ub >> 16) & 1u);
    return ((ua >> 16) & 0xffffu) | (ub & 0xffff0000u);
}

// ---------- prep: e,r -> bf16 + degree histogram ----------
__global__ void prep_kernel(const float* __restrict__ e,
                            const float* __restrict__ r,
                            const int* __restrict__ a,
                            uint2* __restrict__ e16,
                            uint2* __restrict__ r16,
                            int* __restrict__ deg,
                            int n_e4, int n_r4, int n_entries) {
    int gid = blockIdx.x * blockDim.x + threadIdx.x;
    if (gid < n_entries) atomicAdd(&deg[a[gid]], 1);
    if (gid < n_r4) {
        const float4 v = ((const float4*)r)[gid];
        uint2 p;
        p.x = bf16pack2(v.x, v.y);
        p.y = bf16pack2(v.z, v.w);
        r16[gid] = p;
    }
    if (gid >= n_e4) return;
    const float4 v = ((const float4*)e)[gid];
    uint2 p;
    p.x = bf16pack2(v.x, v.y);
    p.y = bf16pack2(v.z, v.w);
    e16[gid] = p;
}

// ---------- multi-block exclusive scan over deg[n] ----------
__global__ void scanA_kernel(const int* __restrict__ deg, int* __restrict__ bsum,
                             int n) {
    __shared__ int wsum[16];
    int t = threadIdx.x, lane = t & 63, w = t >> 6;
    int i = blockIdx.x * SCAN_TILE + t;
    int v = (i < n) ? deg[i] : 0;
    #pragma unroll
    for (int off = 32; off > 0; off >>= 1) v += __shfl_down(v, off, 64);
    if (lane == 0) wsum[w] = v;
    __syncthreads();
    if (t == 0) {
        int s = 0;
        #pragma unroll
        for (int k = 0; k < 16; ++k) s += wsum[k];
        bsum[blockIdx.x] = s;
    }
}

// single small block: exclusive scan of bsum[nblk] -> bbase; offs[n]=total
__global__ void scanB_kernel(int* __restrict__ bsum, int* __restrict__ bbase,
                             int* __restrict__ offs, int nblk, int n) {
    // nblk <= 1024; serial in one thread is fine (tiny)
    if (threadIdx.x == 0) {
        int run = 0;
        for (int b = 0; b < nblk; ++b) {
            bbase[b] = run;
            run += bsum[b];
        }
        offs[n] = run;
    }
}

__global__ void scanC_kernel(int* __restrict__ deg, int* __restrict__ offs,
                             const int* __restrict__ bbase, int n) {
    __shared__ int wsum[16];
    int t = threadIdx.x, lane = t & 63, w = t >> 6;
    int i = blockIdx.x * SCAN_TILE + t;
    int v = (i < n) ? deg[i] : 0;
    int x = v;
    #pragma unroll
    for (int off = 1; off < 64; off <<= 1) {
        int y = __shfl_up(x, off, 64);
        if (lane >= off) x += y;
    }
    if (lane == 63) wsum[w] = x;
    __syncthreads();
    if (w == 0 && lane < 16) {
        int s = wsum[lane];
        #pragma unroll
        for (int off = 1; off < 16; off <<= 1) {
            int y = __shfl_up(s, off, 64);
            if (lane >= off) s += y;
        }
        wsum[lane] = s;
    }
    __syncthreads();
    int wbase = (w == 0) ? 0 : wsum[w - 1];
    if (i < n) {
        int excl = x - v + wbase + bbase[blockIdx.x];
        offs[i] = excl;
        deg[i] = excl;   // cursor for fill
    }
}

// ---------- fill packed CSR entries ----------
__global__ void fill_kernel(const int* __restrict__ a, int* __restrict__ cursor,
                            int2* __restrict__ pl, int n_entries) {
    int k = blockIdx.x * blockDim.x + threadIdx.x;
    if (k >= n_entries) return;
    int edge = k >> 1, j = k & 1;
    int other  = a[2 * edge + j];
    int center = a[2 * edge + (j ^ 1)];
    int pos = atomicAdd(&cursor[center], 1);
    pl[pos] = make_int2(edge, other);
}

// ---------- gather: one wave per node, bf16 e and r ----------
__global__ __launch_bounds__(256) void gather_kernel(
    const unsigned* __restrict__ e16, const unsigned* __restrict__ r16,
    const int* __restrict__ offs, const int2* __restrict__ pl,
    float* __restrict__ out, int n_nodes) {
    int n = blockIdx.x * 4 + (threadIdx.x >> 6);
    if (n >= n_nodes) return;
    int lane = threadIdx.x & 63;      // feats 2*lane, 2*lane+1
    int start = offs[n];
    int end = offs[n + 1];
    float accx = 0.f, accy = 0.f;
    int i = start;
    for (; i + 4 <= end; i += 4) {
        int2 p0 = pl[i];
        int2 p1 = pl[i + 1];
        int2 p2 = pl[i + 2];
        int2 p3 = pl[i + 3];
        unsigned ew0 = e16[(size_t)p0.x * 64 + lane];
        unsigned rw0 = r16[(size_t)p0.y * 64 + lane];
        unsigned ew1 = e16[(size_t)p1.x * 64 + lane];
        unsigned rw1 = r16[(size_t)p1.y * 64 + lane];
        unsigned ew2 = e16[(size_t)p2.x * 64 + lane];
        unsigned rw2 = r16[(size_t)p2.y * 64 + lane];
        unsigned ew3 = e16[(size_t)p3.x * 64 + lane];
        unsigned rw3 = r16[(size_t)p3.y * 64 + lane];
        accx += __uint_as_float(ew0 << 16) * __uint_as_float(rw0 << 16);
        accy += __uint_as_float(ew0 & 0xffff0000u) * __uint_as_float(rw0 & 0xffff0000u);
        accx += __uint_as_float(ew1 << 16) * __uint_as_float(rw1 << 16);
        accy += __uint_as_float(ew1 & 0xffff0000u) * __uint_as_float(rw1 & 0xffff0000u);
        accx += __uint_as_float(ew2 << 16) * __uint_as_float(rw2 << 16);
        accy += __uint_as_float(ew2 & 0xffff0000u) * __uint_as_float(rw2 & 0xffff0000u);
        accx += __uint_as_float(ew3 << 16) * __uint_as_float(rw3 << 16);
        accy += __uint_as_float(ew3 & 0xffff0000u) * __uint_as_float(rw3 & 0xffff0000u);
    }
    for (; i < end; ++i) {
        int2 p0 = pl[i];
        unsigned ew0 = e16[(size_t)p0.x * 64 + lane];
        unsigned rw0 = r16[(size_t)p0.y * 64 + lane];
        accx += __uint_as_float(ew0 << 16) * __uint_as_float(rw0 << 16);
        accy += __uint_as_float(ew0 & 0xffff0000u) * __uint_as_float(rw0 & 0xffff0000u);
    }
    float2 res;
    res.x = accx;
    res.y = accy;
    *((float2*)(out + (size_t)n * D_FEAT) + lane) = res;
}

// ---------- fallback 1: fp32 gather (round-3 path) ----------
__global__ void hist_kernel(const int* __restrict__ a, int* __restrict__ deg,
                            int n_elems) {
    int i = blockIdx.x * blockDim.x + threadIdx.x;
    if (i < n_elems) atomicAdd(&deg[a[i]], 1);
}

__global__ __launch_bounds__(256) void gather_f32_kernel(
    const float* __restrict__ r, const float* __restrict__ e,
    const int* __restrict__ offs, const int2* __restrict__ pl,
    float* __restrict__ out, int n_nodes) {
    int n = blockIdx.x * 4 + (threadIdx.x >> 6);
    if (n >= n_nodes) return;
    int lane = threadIdx.x & 63;
    int start = offs[n];
    int end = offs[n + 1];
    float accx = 0.f, accy = 0.f;
    for (int i = start; i < end; ++i) {
        int2 p0 = pl[i];
        float2 ev0 = *((const float2*)(e + (size_t)p0.x * D_FEAT) + lane);
        float2 rv0 = *((const float2*)(r + (size_t)p0.y * D_FEAT) + lane);
        accx += ev0.x * rv0.x;
        accy += ev0.y * rv0.y;
    }
    float2 res;
    res.x = accx;
    res.y = accy;
    *((float2*)(out + (size_t)n * D_FEAT) + lane) = res;
}

// ---------- fallback 2: atomic scatter (round-1 path) ----------
__global__ void mp_scatter_kernel(const float* __restrict__ r,
                                  const float* __restrict__ e,
                                  const int* __restrict__ a,
                                  float* __restrict__ out,
                                  int n_edges) {
    long long gid = (long long)blockIdx.x * blockDim.x + threadIdx.x;
    int edge = (int)(gid >> 7);
    int feat = (int)(gid & 127);
    if (edge >= n_edges) return;
    int s = a[2 * edge];
    int d = a[2 * edge + 1];
    float ev = e[(long long)edge * D_FEAT + feat];
    float rs = r[(long long)s * D_FEAT + feat];
    float rd = r[(long long)d * D_FEAT + feat];
    atomicAdd(&out[(long long)d * D_FEAT + feat], rs * ev);
    atomicAdd(&out[(long long)s * D_FEAT + feat], rd * ev);
}

extern "C" void kernel_launch(void* const* d_in, const int* in_sizes, int n_in,
                              void* d_out, int out_size, void* d_ws, size_t ws_size,
                              hipStream_t stream) {
    const float* r = (const float*)d_in[0];
    const float* e = (const float*)d_in[1];
    const int*   a = (const int*)d_in[2];
    float* out = (float*)d_out;

    int n_nodes   = in_sizes[0] / D_FEAT;
    int n_edges   = in_sizes[1] / D_FEAT;
    int n_entries = 2 * n_edges;
    int n_e4      = in_sizes[1] / 4;    // float4 groups of e
    int n_r4      = in_sizes[0] / 4;    // float4 groups of r

    int block = 256;
    int grid_e = (n_entries + block - 1) / block;
    int nblk_scan = (n_nodes + SCAN_TILE - 1) / SCAN_TILE;

    // ---- main path ws layout:
    //   e16[n_e4 uint2] | r16[n_r4 uint2] | deg[N] | offs[N+1] |
    //   bsum[nblk] | bbase[nblk] | pad | pl[2E int2]
    {
        size_t ints_head = (size_t)n_nodes + (size_t)(n_nodes + 1)
                         + 2 * (size_t)nblk_scan;
        ints_head = (ints_head + 1) & ~(size_t)1;
        size_t need = ((size_t)n_e4 + (size_t)n_r4) * sizeof(uint2)
                    + ints_head * sizeof(int)
                    + (size_t)n_entries * sizeof(int2);
        if (ws_size >= need && nblk_scan <= 1024) {
            uint2* e16  = (uint2*)d_ws;
            uint2* r16  = e16 + n_e4;
            int*   deg  = (int*)(r16 + n_r4);
            int*   offs = deg + n_nodes;
            int*   bsum = offs + n_nodes + 1;
            int*   bbase= bsum + nblk_scan;
            int2*  pl   = (int2*)((int*)(r16 + n_r4) + ints_head);

            hipMemsetAsync(deg, 0, (size_t)n_nodes * sizeof(int), stream);
            int grid_p = (n_e4 + block - 1) / block;
            prep_kernel<<<grid_p, block, 0, stream>>>(e, r, a, e16, r16, deg,
                                                      n_e4, n_r4, n_entries);
            scanA_kernel<<<nblk_scan, SCAN_TILE, 0, stream>>>(deg, bsum, n_nodes);
            scanB_kernel<<<1, 64, 0, stream>>>(bsum, bbase, offs, nblk_scan,
                                               n_nodes);
            scanC_kernel<<<nblk_scan, SCAN_TILE, 0, stream>>>(deg, offs, bbase,
                                                              n_nodes);
            fill_kernel<<<grid_e, block, 0, stream>>>(a, deg, pl, n_entries);
            int grid_g = (n_nodes + 3) / 4;
            gather_kernel<<<grid_g, 256, 0, stream>>>(
                (const unsigned*)e16, (const unsigned*)r16, offs, pl, out,
                n_nodes);
            return;
        }
    }

    // ---- fallback 1: fp32 gather
    {
        size_t ints_head = (size_t)n_nodes + (size_t)(n_nodes + 1)
                         + 2 * (size_t)nblk_scan;
        ints_head = (ints_head + 1) & ~(size_t)1;
        size_t need = ints_head * sizeof(int) + (size_t)n_entries * sizeof(int2);
        if (ws_size >= need && nblk_scan <= 1024) {
            int*  deg  = (int*)d_ws;
            int*  offs = deg + n_nodes;
            int*  bsum = offs + n_nodes + 1;
            int*  bbase= bsum + nblk_scan;
            int2* pl   = (int2*)((int*)d_ws + ints_head);

            hipMemsetAsync(deg, 0, (size_t)n_nodes * sizeof(int), stream);
            hist_kernel<<<grid_e, block, 0, stream>>>(a, deg, n_entries);
            scanA_kernel<<<nblk_scan, SCAN_TILE, 0, stream>>>(deg, bsum, n_nodes);
            scanB_kernel<<<1, 64, 0, stream>>>(bsum, bbase, offs, nblk_scan,
                                               n_nodes);
            scanC_kernel<<<nblk_scan, SCAN_TILE, 0, stream>>>(deg, offs, bbase,
                                                              n_nodes);
            fill_kernel<<<grid_e, block, 0, stream>>>(a, deg, pl, n_entries);
            int grid_g = (n_nodes + 3) / 4;
            gather_f32_kernel<<<grid_g, 256, 0, stream>>>(r, e, offs, pl, out,
                                                          n_nodes);
            return;
        }
    }

    // ---- fallback 2: atomic scatter
    hipMemsetAsync(d_out, 0, (size_t)out_size * sizeof(float), stream);
    long long total = (long long)n_edges * D_FEAT;
    long long grid = (total + block - 1) / block;
    mp_scatter_kernel<<<(int)grid, block, 0, stream>>>(r, e, a, out, n_edges);
}